// Round 6
// baseline (402.913 us; speedup 1.0000x reference)
//
#include <hip/hip_runtime.h>
#include <hip/hip_bf16.h>

// ---------------------------------------------------------------------------
// SinkhornLinear: W = sinkhorn(weight) [1024x1024], out = x @ W^T
// x: [8,4096,1024] fp32 -> M=32768, K=1024, N=1024, out fp32.
//
// Session facts (measured):
//   - Every grid-wide exchange costs ~18-21us when it goes through a dispatch
//     boundary OR a __threadfence barrier (R0/R2/R5 dispatch gaps ~20us at any
//     grid size; R8 atomic+fence barrier 21us; R6 cg::sync 108us). Constant
//     matches an L2 writeback-invalidate (per-XCD L2s non-coherent).
//   - gemm_bb (bf16 A+B via global_load_lds, XOR-swizzled conflict-free,
//     BK=64 single-buffer): 110us, 0 bank conflicts, FETCH 67MB (minimal).
//
// R11: flush-free persistent Sinkhorn (1 node instead of 11):
//   - R8's verified multiplicative math (u=exp(-.5C), v=exp(-.5R), E=exp(8w)
//     in regs; v'=sqrt(v)*rsqrt(E u); u'=sqrt(u)*rsqrt(E^T v)).
//   - u/v exchanged via RELAXED AGENT atomics (sc0+sc1: bypass L1+L2, commit
//     at coherent point) -> NO threadfence, NO wbinv.
//   - barrier: per-thread vmcnt(0) + syncthreads, then thread0 relaxed-agent
//     fetch_add + bounded spin on relaxed-agent load. Epoch counters zeroed
//     by a 64B memset node each replay.
//   - X fp32->bf16 conversion sliced into the barrier-wait of iters 0..7
//     (hides both the spin and the 192MB of conversion traffic).
//   - Wb = E*v*u -> bf16 in the tail (make_w eliminated).
// Fallback (coop rejected / small ws): R10 multi-dispatch path (verified 377).
// ---------------------------------------------------------------------------

typedef __attribute__((ext_vector_type(8))) short short8;   // 8 bf16 = 4 VGPRs
typedef __attribute__((ext_vector_type(4))) float f32x4;

// packed fp32x2 -> bf16x2 (hardware cvt_pk, round-to-nearest-even)
__device__ inline unsigned int pk2(float a, float b) {
  __hip_bfloat162 h = __float22bfloat162_rn(make_float2(a, b));
  union { __hip_bfloat162 h; unsigned int u; } cv;
  cv.h = h;
  return cv.u;
}

// coherent (L1+L2-bypassing) scalar exchange ops
__device__ __forceinline__ void stc(float* p, float v) {
  __hip_atomic_store(p, v, __ATOMIC_RELAXED, __HIP_MEMORY_SCOPE_AGENT);
}
__device__ __forceinline__ float ldc(const float* p) {
  return __hip_atomic_load(p, __ATOMIC_RELAXED, __HIP_MEMORY_SCOPE_AGENT);
}

// ---------------------------------------------------------------------------
// Persistent fused Sinkhorn + X cvt + W materialization. 256 blocks x 256.
// Block k owns rows 4k..4k+3 (wave wv -> row 4k+wv, lane covers 16 cols)
// and cols 4k..4k+3 (thread t -> rows 4t..4t+3 slab). R8 layout, verified.
// ---------------------------------------------------------------------------
__global__ __launch_bounds__(256, 1) void sinkhorn_persist(
    const float* __restrict__ w,
    int* __restrict__ bar,             // epoch counters, zeroed each replay
    float* __restrict__ ubuf,          // [2][1024] coherent exchange
    float* __restrict__ vbuf,          // [2][1024]
    unsigned short* __restrict__ Wb,   // bf16 W out
    const float* __restrict__ X,
    unsigned short* __restrict__ Xb) { // bf16 X out
  __shared__ float uL[1024];
  __shared__ float vL[1024];
  __shared__ float redC[4][4];
  const int k = blockIdx.x;
  const int t = threadIdx.x;
  const int l = t & 63, wv = t >> 6;
  const int row = 4 * k + wv;

  // --- one-time: E row slice (coalesced) + E col slab (strided, one-time) ---
  float er[16];
  {
    const float* rp = w + (size_t)row * 1024 + l * 16;
    #pragma unroll
    for (int q = 0; q < 4; ++q) {
      float4 v4 = *(const float4*)(rp + q * 4);
      er[q * 4 + 0] = __expf(8.f * v4.x);
      er[q * 4 + 1] = __expf(8.f * v4.y);
      er[q * 4 + 2] = __expf(8.f * v4.z);
      er[q * 4 + 3] = __expf(8.f * v4.w);
    }
  }
  float ecs[4][4];
  {
    #pragma unroll
    for (int q = 0; q < 4; ++q) {
      float4 v4 = *(const float4*)(w + (size_t)(4 * t + q) * 1024 + 4 * k);
      ecs[q][0] = __expf(8.f * v4.x);
      ecs[q][1] = __expf(8.f * v4.y);
      ecs[q][2] = __expf(8.f * v4.z);
      ecs[q][3] = __expf(8.f * v4.w);
    }
  }

  float vold = 1.f;   // authoritative: lane 0 of wave wv (row 4k+wv)
  float uold = 1.f;   // authoritative: wave 0, lanes 0..3 (col 4k+l)

  for (int it = 0; it < 10; ++it) {
    const int rsl = it & 1;          // slot written by previous iter
    const int wsl = (it + 1) & 1;
    float ul[16], vvr[4];
    if (it == 0) {
      #pragma unroll
      for (int q = 0; q < 16; ++q) ul[q] = 1.f;
      vvr[0] = vvr[1] = vvr[2] = vvr[3] = 1.f;
    } else {
      // stage u (XOR-swizzled chunks; read l*4+q would be 32-way unswizzled)
      // and v (natural) through LDS; feed with coherent loads.
      {
        float u0 = ldc(ubuf + rsl * 1024 + t * 4);
        float u1 = ldc(ubuf + rsl * 1024 + t * 4 + 1);
        float u2 = ldc(ubuf + rsl * 1024 + t * 4 + 2);
        float u3 = ldc(ubuf + rsl * 1024 + t * 4 + 3);
        float v0 = ldc(vbuf + rsl * 1024 + t * 4);
        float v1 = ldc(vbuf + rsl * 1024 + t * 4 + 1);
        float v2 = ldc(vbuf + rsl * 1024 + t * 4 + 2);
        float v3 = ldc(vbuf + rsl * 1024 + t * 4 + 3);
        int cp = t ^ ((t >> 3) & 7);
        *(float4*)(uL + cp * 4) = make_float4(u0, u1, u2, u3);
        *(float4*)(vL + t * 4) = make_float4(v0, v1, v2, v3);
      }
      __syncthreads();
      #pragma unroll
      for (int q = 0; q < 4; ++q) {
        int c = l * 4 + q;
        int cp = c ^ ((c >> 3) & 7);
        float4 u4 = *(const float4*)(uL + cp * 4);
        ul[q * 4 + 0] = u4.x; ul[q * 4 + 1] = u4.y;
        ul[q * 4 + 2] = u4.z; ul[q * 4 + 3] = u4.w;
      }
      float4 v4 = *(const float4*)(vL + t * 4);
      vvr[0] = v4.x; vvr[1] = v4.y; vvr[2] = v4.z; vvr[3] = v4.w;
    }

    // row sum: rs = sum_j E[row][j]*u[j]
    float rs = 0.f;
    #pragma unroll
    for (int q = 0; q < 16; ++q) rs += er[q] * ul[q];
    #pragma unroll
    for (int off = 32; off > 0; off >>= 1) rs += __shfl_down(rs, off);

    // col partials over this thread's 4 rows
    float cs0 = 0.f, cs1 = 0.f, cs2 = 0.f, cs3 = 0.f;
    #pragma unroll
    for (int q = 0; q < 4; ++q) {
      cs0 += ecs[q][0] * vvr[q]; cs1 += ecs[q][1] * vvr[q];
      cs2 += ecs[q][2] * vvr[q]; cs3 += ecs[q][3] * vvr[q];
    }
    #pragma unroll
    for (int off = 32; off > 0; off >>= 1) {
      cs0 += __shfl_down(cs0, off); cs1 += __shfl_down(cs1, off);
      cs2 += __shfl_down(cs2, off); cs3 += __shfl_down(cs3, off);
    }
    if (l == 0) {
      redC[wv][0] = cs0; redC[wv][1] = cs1;
      redC[wv][2] = cs2; redC[wv][3] = cs3;
      vold = sqrtf(vold) * rsqrtf(rs);
      stc(vbuf + wsl * 1024 + row, vold);
    }
    __syncthreads();
    if (wv == 0 && l < 4) {
      float tot = redC[0][l] + redC[1][l] + redC[2][l] + redC[3][l];
      uold = sqrtf(uold) * rsqrtf(tot);
      stc(ubuf + wsl * 1024 + 4 * k + l, uold);
    }

    // --- flush-free barrier, spin hidden under X-conversion slice ---
    asm volatile("s_waitcnt vmcnt(0)" ::: "memory");   // my stores committed
    __syncthreads();                                   // whole block committed
    if (t == 0)
      __hip_atomic_fetch_add(bar + it, 1, __ATOMIC_RELAXED, __HIP_MEMORY_SCOPE_AGENT);
    if (it < 8) {
      // convert 16384 elems of X (block chunk) while other blocks arrive
      const size_t base = (size_t)k * 131072 + (size_t)it * 16384;
      #pragma unroll
      for (int r2 = 0; r2 < 8; ++r2) {
        size_t e = base + (size_t)(r2 * 256 + t) * 8;
        float4 a = *(const float4*)(X + e);
        float4 c = *(const float4*)(X + e + 4);
        uint4 o;
        o.x = pk2(a.x, a.y); o.y = pk2(a.z, a.w);
        o.z = pk2(c.x, c.y); o.w = pk2(c.z, c.w);
        *(uint4*)(Xb + e) = o;
      }
    }
    if (t == 0) {
      int spins = 0;
      while (__hip_atomic_load(bar + it, __ATOMIC_RELAXED, __HIP_MEMORY_SCOPE_AGENT) < 256) {
        __builtin_amdgcn_s_sleep(2);
        if (++spins > (1 << 16)) break;   // fail visibly, never hang
      }
    }
    __syncthreads();
  }
  // final u,v in slot 0 (iter 9 wrote wsl=0)

  // tail: Wb[row][j] = E[row][j]*v[row]*u[j] -> bf16
  {
    float u0 = ldc(ubuf + t * 4);
    float u1 = ldc(ubuf + t * 4 + 1);
    float u2 = ldc(ubuf + t * 4 + 2);
    float u3 = ldc(ubuf + t * 4 + 3);
    int cp = t ^ ((t >> 3) & 7);
    *(float4*)(uL + cp * 4) = make_float4(u0, u1, u2, u3);
  }
  __syncthreads();
  const float vfin = __shfl(vold, 0);
  unsigned int o[8];
  #pragma unroll
  for (int q = 0; q < 4; ++q) {
    int c = l * 4 + q;
    int cp = c ^ ((c >> 3) & 7);
    float4 u4 = *(const float4*)(uL + cp * 4);
    o[q * 2 + 0] = pk2(er[q * 4 + 0] * vfin * u4.x, er[q * 4 + 1] * vfin * u4.y);
    o[q * 2 + 1] = pk2(er[q * 4 + 2] * vfin * u4.z, er[q * 4 + 3] * vfin * u4.w);
  }
  unsigned short* wp = Wb + (size_t)row * 1024 + l * 16;
  *(uint4*)(wp) = *(uint4*)(o);
  *(uint4*)(wp + 8) = *(uint4*)(o + 4);
}

// ---------------------------------------------------------------------------
// Fallback path kernels (R10, verified 377us).
// ---------------------------------------------------------------------------
__global__ void sinkhorn_step(const float* __restrict__ w,
                              const float* __restrict__ Rin,
                              const float* __restrict__ Cin,
                              float* __restrict__ Rout,
                              float* __restrict__ Cout,
                              int first,
                              const float* __restrict__ X,
                              unsigned short* __restrict__ Xb,
                              int do_cvt) {
  __shared__ float4 red4[256];
  const int tid = threadIdx.x;
  const int b = blockIdx.x;
  const int lane = tid & 63, wv = tid >> 6;
  if (b < 256) {
    const int row = 4 * b + wv;
    const float* rp = w + (size_t)row * 1024 + lane * 16;
    float s = 0.f;
    #pragma unroll
    for (int q = 0; q < 4; ++q) {
      float4 v4 = *(const float4*)(rp + q * 4);
      float4 c4 = make_float4(0.f, 0.f, 0.f, 0.f);
      if (!first) c4 = *(const float4*)(Cin + lane * 16 + q * 4);
      s += __expf(8.f * v4.x - 0.5f * c4.x) + __expf(8.f * v4.y - 0.5f * c4.y)
         + __expf(8.f * v4.z - 0.5f * c4.z) + __expf(8.f * v4.w - 0.5f * c4.w);
    }
    #pragma unroll
    for (int off = 32; off > 0; off >>= 1) s += __shfl_down(s, off);
    if (lane == 0)
      Rout[row] = (first ? 0.f : 0.5f * Rin[row]) + __logf(s);
  } else if (b < 320) {
    const int cb = b - 256;
    const int c0 = cb * 16;
    const int rowg = tid >> 2, cg = tid & 3;
    const float* wp = w + (size_t)rowg * 1024 + c0 + cg * 4;
    float ax = 0.f, ay = 0.f, az = 0.f, aw = 0.f;
    #pragma unroll 4
    for (int p = 0; p < 16; ++p) {
      float4 wv4 = *(const float4*)(wp + (size_t)p * 64 * 1024);
      float rp = first ? 0.f : Rin[rowg + p * 64];
      float h = 0.5f * rp;
      ax += __expf(8.f * wv4.x - h);
      ay += __expf(8.f * wv4.y - h);
      az += __expf(8.f * wv4.z - h);
      aw += __expf(8.f * wv4.w - h);
    }
    red4[tid] = make_float4(ax, ay, az, aw);
    __syncthreads();
    if (tid < 16) {
      const int g = tid >> 2, e = tid & 3;
      float s = 0.f;
      #pragma unroll 8
      for (int q = 0; q < 64; ++q)
        s += ((const float*)&red4[q * 4 + g])[e];
      const int col = c0 + tid;
      Cout[col] = (first ? 0.f : 0.5f * Cin[col]) + __logf(s);
    }
  } else if (do_cvt) {
    const size_t idx0 = (size_t)(b - 320) * 256 + tid;
    #pragma unroll
    for (int it = 0; it < 8; ++it) {
      size_t e = (it * 524288ull + idx0) * 8;
      float4 a = *(const float4*)(X + e);
      float4 c = *(const float4*)(X + e + 4);
      uint4 o;
      o.x = pk2(a.x, a.y); o.y = pk2(a.z, a.w);
      o.z = pk2(c.x, c.y); o.w = pk2(c.z, c.w);
      *(uint4*)(Xb + e) = o;
    }
  }
}

__global__ void make_w(const float* __restrict__ w, const float* __restrict__ R,
                       const float* __restrict__ C, unsigned short* __restrict__ Wb) {
  const int i = blockIdx.x;
  const int j = threadIdx.x * 4;
  const float r = 0.5f * R[i];
  float4 v = *(const float4*)(w + (size_t)i * 1024 + j);
  float4 cv = *(const float4*)(C + j);
  unsigned int o[2];
  o[0] = pk2(__expf(8.f * v.x - r - 0.5f * cv.x), __expf(8.f * v.y - r - 0.5f * cv.y));
  o[1] = pk2(__expf(8.f * v.z - r - 0.5f * cv.z), __expf(8.f * v.w - r - 0.5f * cv.w));
  *(uint2*)(Wb + (size_t)i * 1024 + j) = *(uint2*)o;
}

// XCD-group swizzle: id = h*64 + n*8 + c  ->  m-slab = c + 8h, n-slab = n.
__device__ inline void swizzle_mn(int id, int& m0, int& n0) {
  m0 = ((id & 7) + ((id >> 6) << 3)) << 7;
  n0 = ((id >> 3) & 7) << 7;
}

// ---------------------------------------------------------------------------
// gemm_bb: A,B both bf16 via global_load_lds w16, pre-swizzled sources.
// 128x128, BK=64, single-buffered, conflict-free (verified 110us / 0 confl).
// ---------------------------------------------------------------------------
__global__ __launch_bounds__(256) void gemm_bb(const unsigned short* __restrict__ Xb,
                                               const unsigned short* __restrict__ Wb,
                                               float* __restrict__ out) {
  __shared__ unsigned short As[128 * 64];
  __shared__ unsigned short Bs[128 * 64];
  const int tid = threadIdx.x;
  const int lane = tid & 63, wave = tid >> 6;
  const int wm = wave >> 1, wn = wave & 1;
  int m0, n0;
  swizzle_mn(blockIdx.x, m0, n0);

  f32x4 acc[4][4] = {};
  const int fr = lane & 15, kq = lane >> 4;

  for (int t = 0; t < 16; ++t) {
    const int k0 = t * 64;
    #pragma unroll
    for (int is = 0; is < 4; ++is) {
      int idx = is * 256 + tid;
      int lrow = idx >> 3;
      int g = (idx & 7) ^ (lrow & 7);
      const unsigned short* ga = Xb + (size_t)(m0 + lrow) * 1024 + k0 + g * 8;
      const unsigned short* gb = Wb + (size_t)(n0 + lrow) * 1024 + k0 + g * 8;
      unsigned short* la = As + (size_t)(is * 256 + wave * 64) * 8;
      unsigned short* lb = Bs + (size_t)(is * 256 + wave * 64) * 8;
      __builtin_amdgcn_global_load_lds(
          (const __attribute__((address_space(1))) unsigned int*)ga,
          (__attribute__((address_space(3))) unsigned int*)la, 16, 0, 0);
      __builtin_amdgcn_global_load_lds(
          (const __attribute__((address_space(1))) unsigned int*)gb,
          (__attribute__((address_space(3))) unsigned int*)lb, 16, 0, 0);
    }
    __syncthreads();

    #pragma unroll
    for (int kk = 0; kk < 2; ++kk) {
      short8 af[4], bf[4];
      #pragma unroll
      for (int mt = 0; mt < 4; ++mt) {
        int row = wm * 64 + mt * 16 + fr;
        int cp = (kk * 4 + kq) ^ (row & 7);
        af[mt] = *(const short8*)(As + (size_t)row * 64 + cp * 8);
      }
      #pragma unroll
      for (int nt = 0; nt < 4; ++nt) {
        int row = wn * 64 + nt * 16 + fr;
        int cp = (kk * 4 + kq) ^ (row & 7);
        bf[nt] = *(const short8*)(Bs + (size_t)row * 64 + cp * 8);
      }
      #pragma unroll
      for (int mt = 0; mt < 4; ++mt)
        #pragma unroll
        for (int nt = 0; nt < 4; ++nt)
          acc[mt][nt] = __builtin_amdgcn_mfma_f32_16x16x32_bf16(af[mt], bf[nt], acc[mt][nt], 0, 0, 0);
    }
    __syncthreads();
  }

  const int crow0 = m0 + wm * 64 + (lane >> 4) * 4;
  const int ccol0 = n0 + wn * 64 + fr;
  #pragma unroll
  for (int mt = 0; mt < 4; ++mt)
    #pragma unroll
    for (int nt = 0; nt < 4; ++nt)
      #pragma unroll
      for (int r = 0; r < 4; ++r)
        out[(size_t)(crow0 + mt * 16 + r) * 1024 + ccol0 + nt * 16] = acc[mt][nt][r];
}

// ---------------------------------------------------------------------------
// gemm_f: A fp32 -> cvt -> swizzled ds_write; B via global_load_lds.
// ---------------------------------------------------------------------------
__global__ __launch_bounds__(256) void gemm_f(const float* __restrict__ X,
                                              const unsigned short* __restrict__ Wb,
                                              float* __restrict__ out) {
  __shared__ unsigned short As[128 * 64];
  __shared__ unsigned short Bs[128 * 64];
  const int tid = threadIdx.x;
  const int lane = tid & 63, wave = tid >> 6;
  const int wm = wave >> 1, wn = wave & 1;
  int m0, n0;
  swizzle_mn(blockIdx.x, m0, n0);

  f32x4 acc[4][4] = {};
  const int ar = tid >> 1, ah = tid & 1;
  const float* Xrow = X + (size_t)(m0 + ar) * 1024 + ah * 32;
  const int fr = lane & 15, kq = lane >> 4;

  for (int t = 0; t < 16; ++t) {
    const int k0 = t * 64;
    #pragma unroll
    for (int is = 0; is < 4; ++is) {
      int idx = is * 256 + tid;
      int lrow = idx >> 3;
      int g = (idx & 7) ^ (lrow & 7);
      const unsigned short* gb = Wb + (size_t)(n0 + lrow) * 1024 + k0 + g * 8;
      unsigned short* lb = Bs + (size_t)(is * 256 + wave * 64) * 8;
      __builtin_amdgcn_global_load_lds(
          (const __attribute__((address_space(1))) unsigned int*)gb,
          (__attribute__((address_space(3))) unsigned int*)lb, 16, 0, 0);
    }
    #pragma unroll
    for (int q = 0; q < 4; ++q) {
      float4 a = *(const float4*)(Xrow + k0 + q * 8);
      float4 c = *(const float4*)(Xrow + k0 + q * 8 + 4);
      uint4 o;
      o.x = pk2(a.x, a.y); o.y = pk2(a.z, a.w);
      o.z = pk2(c.x, c.y); o.w = pk2(c.z, c.w);
      int cp = (ah * 4 + q) ^ (ar & 7);
      *(uint4*)(As + (size_t)ar * 64 + cp * 8) = o;
    }
    __syncthreads();

    #pragma unroll
    for (int kk = 0; kk < 2; ++kk) {
      short8 af[4], bf[4];
      #pragma unroll
      for (int mt = 0; mt < 4; ++mt) {
        int row = wm * 64 + mt * 16 + fr;
        int cp = (kk * 4 + kq) ^ (row & 7);
        af[mt] = *(const short8*)(As + (size_t)row * 64 + cp * 8);
      }
      #pragma unroll
      for (int nt = 0; nt < 4; ++nt) {
        int row = wn * 64 + nt * 16 + fr;
        int cp = (kk * 4 + kq) ^ (row & 7);
        bf[nt] = *(const short8*)(Bs + (size_t)row * 64 + cp * 8);
      }
      #pragma unroll
      for (int mt = 0; mt < 4; ++mt)
        #pragma unroll
        for (int nt = 0; nt < 4; ++nt)
          acc[mt][nt] = __builtin_amdgcn_mfma_f32_16x16x32_bf16(af[mt], bf[nt], acc[mt][nt], 0, 0, 0);
    }
    __syncthreads();
  }

  const int crow0 = m0 + wm * 64 + (lane >> 4) * 4;
  const int ccol0 = n0 + wn * 64 + fr;
  #pragma unroll
  for (int mt = 0; mt < 4; ++mt)
    #pragma unroll
    for (int nt = 0; nt < 4; ++nt)
      #pragma unroll
      for (int r = 0; r < 4; ++r)
        out[(size_t)(crow0 + mt * 16 + r) * 1024 + ccol0 + nt * 16] = acc[mt][nt][r];
}

// ---------------------------------------------------------------------------
// gemm_b (tiny-ws fallback): W recomputed in B-staging.
// ---------------------------------------------------------------------------
__global__ __launch_bounds__(256) void gemm_b(const float* __restrict__ X,
                                              const float* __restrict__ w,
                                              const float* __restrict__ R,
                                              const float* __restrict__ C,
                                              float* __restrict__ out) {
  __shared__ unsigned short As[128 * 32];
  __shared__ unsigned short Bs[128 * 32];
  const int tid = threadIdx.x;
  const int lane = tid & 63, wave = tid >> 6;
  const int wm = wave >> 1, wn = wave & 1;
  int m0, n0;
  swizzle_mn(blockIdx.x, m0, n0);

  f32x4 acc[4][4] = {};
  const int sr = tid >> 1, sk = (tid & 1) * 16;
  const float* Xrow = X + (size_t)(m0 + sr) * 1024 + sk;
  const float* Wrow = w + (size_t)(n0 + sr) * 1024 + sk;
  const float rpot = 0.5f * R[n0 + sr];

  for (int k0 = 0; k0 < 1024; k0 += 32) {
    float4 vb0 = *(const float4*)(Wrow + k0);
    float4 vb1 = *(const float4*)(Wrow + k0 + 4);
    float4 vb2 = *(const float4*)(Wrow + k0 + 8);
    float4 vb3 = *(const float4*)(Wrow + k0 + 12);
    float4 vc0 = *(const float4*)(C + k0 + sk);
    float4 vc1 = *(const float4*)(C + k0 + sk + 4);
    float4 vc2 = *(const float4*)(C + k0 + sk + 8);
    float4 vc3 = *(const float4*)(C + k0 + sk + 12);
    unsigned int pb[8];
    pb[0] = pk2(__expf(8.f * vb0.x - rpot - 0.5f * vc0.x), __expf(8.f * vb0.y - rpot - 0.5f * vc0.y));
    pb[1] = pk2(__expf(8.f * vb0.z - rpot - 0.5f * vc0.z), __expf(8.f * vb0.w - rpot - 0.5f * vc0.w));
    pb[2] = pk2(__expf(8.f * vb1.x - rpot - 0.5f * vc1.x), __expf(8.f * vb1.y - rpot - 0.5f * vc1.y));
    pb[3] = pk2(__expf(8.f * vb1.z - rpot - 0.5f * vc1.z), __expf(8.f * vb1.w - rpot - 0.5f * vc1.w));
    pb[4] = pk2(__expf(8.f * vb2.x - rpot - 0.5f * vc2.x), __expf(8.f * vb2.y - rpot - 0.5f * vc2.y));
    pb[5] = pk2(__expf(8.f * vb2.z - rpot - 0.5f * vc2.z), __expf(8.f * vb2.w - rpot - 0.5f * vc2.w));
    pb[6] = pk2(__expf(8.f * vb3.x - rpot - 0.5f * vc3.x), __expf(8.f * vb3.y - rpot - 0.5f * vc3.y));
    pb[7] = pk2(__expf(8.f * vb3.z - rpot - 0.5f * vc3.z), __expf(8.f * vb3.w - rpot - 0.5f * vc3.w));
    float4 va0 = *(const float4*)(Xrow + k0);
    float4 va1 = *(const float4*)(Xrow + k0 + 4);
    float4 va2 = *(const float4*)(Xrow + k0 + 8);
    float4 va3 = *(const float4*)(Xrow + k0 + 12);
    unsigned int pa[8];
    pa[0] = pk2(va0.x, va0.y); pa[1] = pk2(va0.z, va0.w);
    pa[2] = pk2(va1.x, va1.y); pa[3] = pk2(va1.z, va1.w);
    pa[4] = pk2(va2.x, va2.y); pa[5] = pk2(va2.z, va2.w);
    pa[6] = pk2(va3.x, va3.y); pa[7] = pk2(va3.z, va3.w);

    *(uint4*)(Bs + sr * 32 + sk)     = *(uint4*)(pb);
    *(uint4*)(Bs + sr * 32 + sk + 8) = *(uint4*)(pb + 4);
    *(uint4*)(As + sr * 32 + sk)     = *(uint4*)(pa);
    *(uint4*)(As + sr * 32 + sk + 8) = *(uint4*)(pa + 4);

    __syncthreads();

    const int kq2 = (lane >> 4) * 8;
    const int fr2 = lane & 15;
    short8 af[4], bf[4];
    #pragma unroll
    for (int t = 0; t < 4; ++t)
      af[t] = *(const short8*)(As + (wm * 64 + t * 16 + fr2) * 32 + kq2);
    #pragma unroll
    for (int t = 0; t < 4; ++t)
      bf[t] = *(const short8*)(Bs + (wn * 64 + t * 16 + fr2) * 32 + kq2);
    #pragma unroll
    for (int mt = 0; mt < 4; ++mt)
      #pragma unroll
      for (int nt = 0; nt < 4; ++nt)
        acc[mt][nt] = __builtin_amdgcn_mfma_f32_16x16x32_bf16(af[mt], bf[nt], acc[mt][nt], 0, 0, 0);

    __syncthreads();
  }

  const int crow0 = m0 + wm * 64 + (lane >> 4) * 4;
  const int ccol0 = n0 + wn * 64 + (lane & 15);
  #pragma unroll
  for (int mt = 0; mt < 4; ++mt)
    #pragma unroll
    for (int nt = 0; nt < 4; ++nt)
      #pragma unroll
      for (int r = 0; r < 4; ++r)
        out[(size_t)(crow0 + mt * 16 + r) * 1024 + ccol0 + nt * 16] = acc[mt][nt][r];
}

extern "C" void kernel_launch(void* const* d_in, const int* in_sizes, int n_in,
                              void* d_out, int out_size, void* d_ws, size_t ws_size,
                              hipStream_t stream) {
  const float* x = (const float*)d_in[0];        // [8,4096,1024] fp32
  const float* weight = (const float*)d_in[1];   // [1024,1024] fp32
  float* out = (float*)d_out;                    // [8,4096,1024] fp32

  // --- persistent path layout: bar 1KB | ubuf 8KB | vbuf 8KB | Wb 2MB | Xb 64MB
  int* bar = (int*)d_ws;
  float* ubufP = (float*)d_ws + 256;
  float* vbufP = ubufP + 2048;
  unsigned short* WbP = (unsigned short*)(vbufP + 2048);
  unsigned short* XbP = WbP + (size_t)1024 * 1024;
  const size_t need_persist =
      1024 + 16 * 1024 + 2 * 1024 * 1024 + (size_t)32768 * 1024 * 2;

  if (ws_size >= need_persist) {
    hipError_t e0 = hipMemsetAsync(bar, 0, 64, stream);
    if (e0 == hipSuccess) {
      const float* warg = weight;
      int* barArg = bar;
      float* uArg = ubufP;
      float* vArg = vbufP;
      unsigned short* WbArg = WbP;
      const float* xArg = x;
      unsigned short* XbArg = XbP;
      void* args[7] = {(void*)&warg, (void*)&barArg, (void*)&uArg,
                       (void*)&vArg, (void*)&WbArg, (void*)&xArg,
                       (void*)&XbArg};
      hipError_t ce = hipLaunchCooperativeKernel((const void*)sinkhorn_persist,
                                                 dim3(256), dim3(256), args, 0,
                                                 stream);
      if (ce == hipSuccess) {
        gemm_bb<<<2048, 256, 0, stream>>>(XbP, WbP, out);
        return;
      }
      (void)hipGetLastError();
    } else {
      (void)hipGetLastError();
    }
  }

  // --- fallback: R10 multi-dispatch path (verified 377us) ---
  float* R0 = (float*)d_ws;
  float* C0 = R0 + 1024;
  float* R1 = C0 + 1024;
  float* C1 = R1 + 1024;
  unsigned short* Wb = (unsigned short*)(C1 + 1024);
  unsigned short* Xb = Wb + (size_t)1024 * 1024;
  const size_t need_small = 16 * 1024 + 2 * 1024 * 1024;
  const size_t need_big = need_small + (size_t)32768 * 1024 * 2;
  const int big = (ws_size >= need_big) ? 1 : 0;
  const int small_ok = (ws_size >= need_small) ? 1 : 0;

  for (int t = 0; t < 10; ++t) {
    const float *Ri, *Ci;
    float *Ro, *Co;
    if ((t & 1) == 0) { Ri = R0; Ci = C0; Ro = R1; Co = C1; }
    else              { Ri = R1; Ci = C1; Ro = R0; Co = C0; }
    const int cvt = (t == 0 && big) ? 1 : 0;
    const int grid = cvt ? 2368 : 320;
    sinkhorn_step<<<grid, 256, 0, stream>>>(weight, Ri, Ci, Ro, Co,
                                            (t == 0) ? 1 : 0, x, Xb, cvt);
  }
  if (small_ok) {
    make_w<<<1024, 256, 0, stream>>>(weight, R0, C0, Wb);
    if (big) gemm_bb<<<2048, 256, 0, stream>>>(Xb, Wb, out);
    else     gemm_f<<<2048, 256, 0, stream>>>(x, Wb, out);
  } else {
    gemm_b<<<2048, 256, 0, stream>>>(x, weight, R0, C0, out);
  }
}